// Round 3
// baseline (3351.740 us; speedup 1.0000x reference)
//
#include <hip/hip_runtime.h>
#include <hip/hip_bf16.h>
#include <stdint.h>

#define N_NODES 300000
#define N_EDGES 4000000
#define IC 128
#define OC 64
#define NREL 7
#define NTYP 4

typedef __attribute__((ext_vector_type(8))) short short8;
typedef __attribute__((ext_vector_type(4))) float f32x4;

__device__ __forceinline__ uint32_t f32_to_bf16_rne(float f) {
    uint32_t b = __float_as_uint(f);
    return (b + 0x7fffu + ((b >> 16) & 1u)) >> 16;
}
__device__ __forceinline__ uint32_t pack_bf16(float lo, float hi) {
    return f32_to_bf16_rne(lo) | (f32_to_bf16_rne(hi) << 16);
}

// ---- K0: x fp32 -> bf16 (8 floats / thread) ----
__global__ void k_cvt_x(const float* __restrict__ x, uint32_t* __restrict__ xb) {
    int i = blockIdx.x * blockDim.x + threadIdx.x;
    const float4* xf = (const float4*)x;
    float4 a = xf[2 * i], b = xf[2 * i + 1];
    uint4 o;
    o.x = pack_bf16(a.x, a.y); o.y = pack_bf16(a.z, a.w);
    o.z = pack_bf16(b.x, b.y); o.w = pack_bf16(b.z, b.w);
    ((uint4*)xb)[i] = o;
}

// ---- K0b: W_rel [7][128][64] ++ W_root [4][128][64] -> Wt bf16 [11][64][128] (o-major, k-contig) ----
__global__ void k_cvt_w(const float* __restrict__ Wrel, const float* __restrict__ Wroot,
                        uint16_t* __restrict__ Wt) {
    int i = blockIdx.x * blockDim.x + threadIdx.x;   // i = rel*8192 + o*128 + k
    int rel = i >> 13, rem = i & 8191, o = rem >> 7, k = rem & 127;
    float v = (rel < NREL) ? Wrel[(rel * IC + k) * OC + o]
                           : Wroot[((rel - NREL) * IC + k) * OC + o];
    Wt[i] = (uint16_t)f32_to_bf16_rne(v);
}

// ---- K1: dst-degree histogram, 4 edges/thread ----
__global__ void k_hist(const int* __restrict__ ei, int* __restrict__ deg) {
    int i = blockIdx.x * 256 + threadIdx.x;
    if (i >= N_EDGES / 4) return;
    int4 d = ((const int4*)(ei + N_EDGES))[i];
    atomicAdd(&deg[d.x], 1);
    atomicAdd(&deg[d.y], 1);
    atomicAdd(&deg[d.z], 1);
    atomicAdd(&deg[d.w], 1);
}

// ---- K2a/b/c: exclusive scan of deg[N_NODES] -> offs ----
__global__ void k_scan1(const int* __restrict__ deg, int* __restrict__ offs,
                        int* __restrict__ bsum) {
    __shared__ int s[1024];
    int t = threadIdx.x, i = blockIdx.x * 1024 + t;
    int v = (i < N_NODES) ? deg[i] : 0;
    s[t] = v; __syncthreads();
    for (int d = 1; d < 1024; d <<= 1) {
        int add = (t >= d) ? s[t - d] : 0;
        __syncthreads();
        s[t] += add;
        __syncthreads();
    }
    if (i < N_NODES) offs[i] = s[t] - v;
    if (t == 1023) bsum[blockIdx.x] = s[t];
}

__global__ void k_scan2(int* __restrict__ bsum, int nblk) {
    __shared__ int s[512];
    int t = threadIdx.x;
    int v = (t < nblk) ? bsum[t] : 0;
    s[t] = v; __syncthreads();
    for (int d = 1; d < 512; d <<= 1) {
        int add = (t >= d) ? s[t - d] : 0;
        __syncthreads();
        s[t] += add;
        __syncthreads();
    }
    if (t < nblk) bsum[t] = s[t] - v;
}

__global__ void k_scan3(int* __restrict__ offs, const int* __restrict__ bsum,
                        int* __restrict__ cur) {
    int i = blockIdx.x * 256 + threadIdx.x;
    if (i < N_NODES) {
        int v = offs[i] + bsum[i >> 10];
        offs[i] = v;
        cur[i] = v;
    }
    if (i == 0) offs[N_NODES] = N_EDGES;
}

// ---- K3: scatter edges into dst-sorted order, packed (src<<6)|(rel<<3)|(dst&7) ----
__global__ void k_scatter(const int* __restrict__ ei, const int* __restrict__ et,
                          int* __restrict__ cur, int* __restrict__ sorted) {
    int i = blockIdx.x * 256 + threadIdx.x;
    if (i >= N_EDGES / 4) return;
    int4 sv = ((const int4*)ei)[i];
    int4 dv = ((const int4*)(ei + N_EDGES))[i];
    int4 rv = ((const int4*)et)[i];
    {
        int pos = atomicAdd(&cur[dv.x], 1);
        sorted[pos] = (sv.x << 6) | (rv.x << 3) | (dv.x & 7);
    }
    {
        int pos = atomicAdd(&cur[dv.y], 1);
        sorted[pos] = (sv.y << 6) | (rv.y << 3) | (dv.y & 7);
    }
    {
        int pos = atomicAdd(&cur[dv.z], 1);
        sorted[pos] = (sv.z << 6) | (rv.z << 3) | (dv.z & 7);
    }
    {
        int pos = atomicAdd(&cur[dv.w], 1);
        sorted[pos] = (sv.w << 6) | (rv.w << 3) | (dv.w & 7);
    }
}

// ---- K4: fused edge-parallel aggregate (LDS fp32 atomics) + MFMA. 1 block = 8 dst. ----
__global__ __launch_bounds__(256, 4)
void k_main(const uint32_t* __restrict__ xb_u, const uint16_t* __restrict__ Wt,
            const int* __restrict__ offs, const int* __restrict__ sorted,
            const int* __restrict__ node_type, const float* __restrict__ b_root,
            float* __restrict__ out) {
    // P: fp32 accumulator planes [7 rel][8 slot][128 feat, permuted]:
    //   word w (w<64) holds feature 2w ; word 64+w holds feature 2w+1
    // After gather it is repacked IN PLACE to bf16 rows of stride 68 uints.
    __shared__ float P[7 * 8 * 128];     // 28 KB
    __shared__ int   cntI[56];           // per-(rel*8+slot) edge counts
    __shared__ float invS[56];
    __shared__ int   nt8[8];

    int t = threadIdx.x, lane = t & 63, wave = t >> 6;
    int d0 = blockIdx.x * 8;

    // zero accumulator planes + counters
    float4* P4 = (float4*)P;
    #pragma unroll
    for (int i = 0; i < 7; ++i) P4[t + i * 256] = float4{0.f, 0.f, 0.f, 0.f};
    if (t < 56) cntI[t] = 0;
    if (t >= 64 && t < 72) nt8[t - 64] = node_type[d0 + (t - 64)];
    __syncthreads();

    // ---- edge-parallel gather: each wave takes every 4th edge (x2 unroll) ----
    int ebase = offs[d0];
    int eend  = offs[d0 + 8];
    int e = ebase + wave;
    for (; e + 4 < eend; e += 8) {
        int recA = sorted[e];
        int recB = sorted[e + 4];
        uint32_t vA = xb_u[(recA >> 6) * 64 + lane];   // 256B coalesced row
        uint32_t vB = xb_u[(recB >> 6) * 64 + lane];
        int pbA = (recA & 63) << 7;     // (rel*8+slot)*128
        int pbB = (recB & 63) << 7;
        if (lane == 0) {
            atomicAdd(&cntI[recA & 63], 1);
            atomicAdd(&cntI[recB & 63], 1);
        }
        atomicAdd(&P[pbA + lane],      __uint_as_float(vA << 16));
        atomicAdd(&P[pbA + 64 + lane], __uint_as_float(vA & 0xffff0000u));
        atomicAdd(&P[pbB + lane],      __uint_as_float(vB << 16));
        atomicAdd(&P[pbB + 64 + lane], __uint_as_float(vB & 0xffff0000u));
    }
    if (e < eend) {
        int rec = sorted[e];
        uint32_t v = xb_u[(rec >> 6) * 64 + lane];
        int pb = (rec & 63) << 7;
        if (lane == 0) atomicAdd(&cntI[rec & 63], 1);
        atomicAdd(&P[pb + lane],      __uint_as_float(v << 16));
        atomicAdd(&P[pb + 64 + lane], __uint_as_float(v & 0xffff0000u));
    }
    __syncthreads();

    if (t < 56) invS[t] = 1.0f / (float)max(cntI[t], 1);
    __syncthreads();

    // ---- scale + repack in place: 56 rows x 64 packed uints, row stride 68 ----
    float tmp[28];
    #pragma unroll
    for (int j = 0; j < 14; ++j) {
        int i = t + j * 256;            // 0..3583
        int row = i >> 6;               // rel*8+slot
        int k2  = i & 63;
        float s = invS[row];
        tmp[2 * j]     = P[(row << 7) + k2] * s;        // feature 2*k2
        tmp[2 * j + 1] = P[(row << 7) + 64 + k2] * s;   // feature 2*k2+1
    }
    __syncthreads();
    uint32_t* Pk = (uint32_t*)P;        // packed bf16 rows, stride 68 uints
    #pragma unroll
    for (int j = 0; j < 14; ++j) {
        int i = t + j * 256;
        int row = i >> 6, k2 = i & 63;
        Pk[row * 68 + k2] = pack_bf16(tmp[2 * j], tmp[2 * j + 1]);
    }
    __syncthreads();

    // ---- MFMA: wave covers out cols [wave*16, wave*16+16) for the 8 dst ----
    const uint16_t* A = (const uint16_t*)P;   // row stride 136 ushorts
    int n = lane & 15, quad = lane >> 4;
    int slot = n & 7;                          // A rows 8..15 duplicate 0..7 (unstored)
    f32x4 c = {0.f, 0.f, 0.f, 0.f};
    const uint16_t* Wb = Wt + (size_t)(wave * 16 + n) * 128;
    for (int rel = 0; rel < NREL; ++rel) {
        #pragma unroll
        for (int kb = 0; kb < 4; ++kb) {
            short8 af = *(const short8*)&A[(rel * 8 + slot) * 136 + kb * 32 + quad * 8];
            short8 bf = *(const short8*)&Wb[rel * 8192 + kb * 32 + quad * 8];
            c = __builtin_amdgcn_mfma_f32_16x16x32_bf16(af, bf, c, 0, 0, 0);
        }
    }
    // root pseudo-relations: x[dst] masked by node type, A-frags straight from global
    int nts = nt8[slot];
    const uint32_t* xrow = xb_u + (size_t)(d0 + slot) * 64;
    #pragma unroll
    for (int tt = 0; tt < NTYP; ++tt) {
        #pragma unroll
        for (int kb = 0; kb < 4; ++kb) {
            uint4 xv = *(const uint4*)&xrow[kb * 16 + quad * 4];
            if (nts != tt) xv = uint4{0u, 0u, 0u, 0u};
            short8 af;
            *(uint4*)&af = xv;
            short8 bf = *(const short8*)&Wb[(NREL + tt) * 8192 + kb * 32 + quad * 8];
            c = __builtin_amdgcn_mfma_f32_16x16x32_bf16(af, bf, c, 0, 0, 0);
        }
    }

    // ---- epilogue: C row m = quad*4+rg (dst slot, only m<8 real), col = n ----
    int o = wave * 16 + n;
    #pragma unroll
    for (int rg = 0; rg < 4; ++rg) {
        int mm = quad * 4 + rg;
        if (mm < 8) {
            int dst = d0 + mm;
            out[dst * 64 + o] = c[rg] + b_root[nt8[mm] * 64 + o];
        }
    }
}

extern "C" void kernel_launch(void* const* d_in, const int* in_sizes, int n_in,
                              void* d_out, int out_size, void* d_ws, size_t ws_size,
                              hipStream_t stream) {
    const float* x      = (const float*)d_in[0];
    const int*   ei     = (const int*)d_in[1];
    const int*   etype  = (const int*)d_in[2];
    const int*   ntype  = (const int*)d_in[3];
    const float* Wrel   = (const float*)d_in[4];
    const float* Wroot  = (const float*)d_in[5];
    const float* broot  = (const float*)d_in[6];
    float* out = (float*)d_out;

    // workspace layout (~96.6 MB total — matches round-1 footprint that passed)
    char* ws = (char*)d_ws;
    size_t p = 0;
    auto take = [&](size_t bytes) { size_t r = p; p += (bytes + 255) & ~(size_t)255; return r; };
    uint32_t* xb     = (uint32_t*)(ws + take((size_t)N_NODES * IC * 2));      // 76.8 MB
    uint16_t* Wt     = (uint16_t*)(ws + take((size_t)(NREL + NTYP) * OC * IC * 2));
    int*      deg    = (int*)(ws + take((size_t)N_NODES * 4));
    int*      offs   = (int*)(ws + take((size_t)(N_NODES + 1) * 4));
    int*      cur    = (int*)(ws + take((size_t)N_NODES * 4));
    int*      bsum   = (int*)(ws + take(4096));
    int*      sorted = (int*)(ws + take((size_t)N_EDGES * 4));
    (void)ws_size; (void)n_in; (void)in_sizes; (void)out_size;

    const int SCAN_BLKS = (N_NODES + 1023) / 1024;   // 293

    k_cvt_x<<<(N_NODES * IC / 8) / 256, 256, 0, stream>>>(x, xb);
    k_cvt_w<<<((NREL + NTYP) * OC * IC) / 256, 256, 0, stream>>>(Wrel, Wroot, Wt);
    hipMemsetAsync(deg, 0, (size_t)N_NODES * 4, stream);
    k_hist<<<(N_EDGES / 4 + 255) / 256, 256, 0, stream>>>(ei, deg);
    k_scan1<<<SCAN_BLKS, 1024, 0, stream>>>(deg, offs, bsum);
    k_scan2<<<1, 512, 0, stream>>>(bsum, SCAN_BLKS);
    k_scan3<<<(N_NODES + 255) / 256, 256, 0, stream>>>(offs, bsum, cur);
    k_scatter<<<(N_EDGES / 4 + 255) / 256, 256, 0, stream>>>(ei, etype, cur, sorted);
    k_main<<<N_NODES / 8, 256, 0, stream>>>(xb, Wt, offs, sorted, ntype, broot, out);
}

// Round 4
// 1600.442 us; speedup vs baseline: 2.0943x; 2.0943x over previous
//
#include <hip/hip_runtime.h>
#include <hip/hip_bf16.h>
#include <stdint.h>

#define N_NODES 300000
#define N_EDGES 4000000
#define IC 128
#define OC 64
#define NREL 7
#define NTYP 4
#define NRELT 11                 // 7 relations + 4 root pseudo-relations
#define NSEG (N_NODES * NREL)    // 2,100,000 (dst*7+rel) segments
#define AS 136                   // A-row stride in ushorts (272B, 16B-aligned)

typedef __attribute__((ext_vector_type(8))) short short8;
typedef __attribute__((ext_vector_type(4))) float f32x4;

__device__ __forceinline__ uint32_t f32_to_bf16_rne(float f) {
    uint32_t b = __float_as_uint(f);
    return (b + 0x7fffu + ((b >> 16) & 1u)) >> 16;
}
__device__ __forceinline__ uint32_t pack_bf16(float lo, float hi) {
    return f32_to_bf16_rne(lo) | (f32_to_bf16_rne(hi) << 16);
}

// ---- K0b: W_rel [7][128][64] ++ W_root [4][128][64] -> Wt bf16 [11][64][128] (o-major, k-contig) ----
__global__ void k_cvt_w(const float* __restrict__ Wrel, const float* __restrict__ Wroot,
                        uint16_t* __restrict__ Wt) {
    int i = blockIdx.x * blockDim.x + threadIdx.x;   // i = rel*8192 + o*128 + k
    int rel = i >> 13, rem = i & 8191, o = rem >> 7, k = rem & 127;
    float v = (rel < NREL) ? Wrel[(rel * IC + k) * OC + o]
                           : Wroot[((rel - NREL) * IC + k) * OC + o];
    Wt[i] = (uint16_t)f32_to_bf16_rne(v);
}

// ---- K1: (dst,rel)-segment histogram, 4 edges/thread ----
__global__ void k_hist(const int* __restrict__ ei, const int* __restrict__ et,
                       int* __restrict__ deg) {
    int i = blockIdx.x * 256 + threadIdx.x;
    if (i >= N_EDGES / 4) return;
    int4 d = ((const int4*)(ei + N_EDGES))[i];
    int4 r = ((const int4*)et)[i];
    atomicAdd(&deg[d.x * 7 + r.x], 1);
    atomicAdd(&deg[d.y * 7 + r.y], 1);
    atomicAdd(&deg[d.z * 7 + r.z], 1);
    atomicAdd(&deg[d.w * 7 + r.w], 1);
}

// ---- K2a/b/c: exclusive scan of deg[NSEG] -> offs ----
__global__ void k_scan1(const int* __restrict__ deg, int* __restrict__ offs,
                        int* __restrict__ bsum) {
    __shared__ int s[1024];
    int t = threadIdx.x, i = blockIdx.x * 1024 + t;
    int v = (i < NSEG) ? deg[i] : 0;
    s[t] = v; __syncthreads();
    for (int d = 1; d < 1024; d <<= 1) {
        int add = (t >= d) ? s[t - d] : 0;
        __syncthreads();
        s[t] += add;
        __syncthreads();
    }
    if (i < NSEG) offs[i] = s[t] - v;
    if (t == 1023) bsum[blockIdx.x] = s[t];
}

__global__ void k_scan2(int* __restrict__ bsum, int nblk) {
    __shared__ int s[1024];
    int t = threadIdx.x;
    int carry = 0;
    for (int c0 = 0; c0 < nblk; c0 += 1024) {
        int i = c0 + t;
        int v = (i < nblk) ? bsum[i] : 0;
        s[t] = v; __syncthreads();
        for (int d = 1; d < 1024; d <<= 1) {
            int add = (t >= d) ? s[t - d] : 0;
            __syncthreads();
            s[t] += add;
            __syncthreads();
        }
        if (i < nblk) bsum[i] = carry + s[t] - v;
        int tot = s[1023];
        __syncthreads();
        carry += tot;
    }
}

__global__ void k_scan3(int* __restrict__ offs, const int* __restrict__ bsum,
                        int* __restrict__ cur) {
    int i = blockIdx.x * 256 + threadIdx.x;
    if (i < NSEG) {
        int v = offs[i] + bsum[i >> 10];
        offs[i] = v;
        cur[i] = v;
    }
    if (i == 0) offs[NSEG] = N_EDGES;
}

// ---- K3: scatter src into (dst,rel)-sorted order ----
__global__ void k_scatter(const int* __restrict__ ei, const int* __restrict__ et,
                          int* __restrict__ cur, int* __restrict__ sorted) {
    int i = blockIdx.x * 256 + threadIdx.x;
    if (i >= N_EDGES / 4) return;
    int4 sv = ((const int4*)ei)[i];
    int4 dv = ((const int4*)(ei + N_EDGES))[i];
    int4 rv = ((const int4*)et)[i];
    { int pos = atomicAdd(&cur[dv.x * 7 + rv.x], 1); sorted[pos] = sv.x; }
    { int pos = atomicAdd(&cur[dv.y * 7 + rv.y], 1); sorted[pos] = sv.y; }
    { int pos = atomicAdd(&cur[dv.z * 7 + rv.z], 1); sorted[pos] = sv.z; }
    { int pos = atomicAdd(&cur[dv.w * 7 + rv.w], 1); sorted[pos] = sv.w; }
}

// ---- K4: atomic-free fused aggregate + MFMA. 1 block = 16 dst, wave owns 4 dst (28 segs). ----
__global__ __launch_bounds__(256, 4)
void k_main(const float* __restrict__ x, const uint16_t* __restrict__ Wt,
            const int* __restrict__ offs, const int* __restrict__ sorted,
            const int* __restrict__ node_type, const float* __restrict__ b_root,
            float* __restrict__ out) {
    __shared__ uint16_t A[NREL * 16 * AS];   // 30,464 B; row = rel*16 + slot, k-contig
    __shared__ int nt16[16];
    int t = threadIdx.x, lane = t & 63, wave = t >> 6;
    int d0 = blockIdx.x * 16;
    if (t < 16) nt16[t] = node_type[d0 + t];
    uint32_t* Pk = (uint32_t*)A;             // row stride 68 uints

    // wave's 28 segment boundaries: offs[(d0+wave*4)*7 + 0..28]
    int segbase = (d0 + wave * 4) * 7;
    int off_l = (lane < 29) ? offs[segbase + lane] : 0;
    int mybase = __shfl(off_l, 0);
    int myend  = __shfl(off_l, 28);

    // batched edge records (src ids), 64 at a time, lane-strided
    int bcur = mybase;
    int rec = (mybase + lane < myend) ? sorted[mybase + lane] : 0;
    int sp = 0;                              // current local segment
    int e_end = __shfl(off_l, 1);
    float a0 = 0.f, a1 = 0.f;                // lane's feature pair (2*lane, 2*lane+1)
    const float* xl = x + lane * 2;

    for (int cb = mybase; cb < myend; cb += 4) {
        if (cb >= bcur + 64) {               // uniform refill, chunks never straddle
            bcur = cb;
            rec = (bcur + lane < myend) ? sorted[bcur + lane] : 0;
        }
        int nn = min(4, myend - cb);
        float2 v[4];
        #pragma unroll
        for (int j = 0; j < 4; ++j) {
            if (j < nn) {
                int src = __shfl(rec, cb + j - bcur);           // uniform idx
                v[j] = *(const float2*)(xl + (size_t)src * 128); // 512B/wave row
            }
        }
        #pragma unroll
        for (int j = 0; j < 4; ++j) {
            if (j < nn) {
                while (cb + j == e_end && sp < 27) {   // uniform segment flush
                    int e_beg = __shfl(off_l, sp);
                    float inv = 1.0f / (float)max(e_end - e_beg, 1);
                    int slot = wave * 4 + sp / 7, rel = sp % 7;
                    Pk[(rel * 16 + slot) * 68 + lane] = pack_bf16(a0 * inv, a1 * inv);
                    a0 = 0.f; a1 = 0.f;
                    ++sp;
                    e_end = __shfl(off_l, sp + 1);
                }
                a0 += v[j].x; a1 += v[j].y;
            }
        }
    }
    // tail: flush open segment + remaining (possibly empty) segments
    for (; sp < 28; ++sp) {
        int e_beg = __shfl(off_l, sp);
        int e_en  = __shfl(off_l, sp + 1);
        float inv = 1.0f / (float)max(e_en - e_beg, 1);
        int slot = wave * 4 + sp / 7, rel = sp % 7;
        Pk[(rel * 16 + slot) * 68 + lane] = pack_bf16(a0 * inv, a1 * inv);
        a0 = 0.f; a1 = 0.f;
    }
    __syncthreads();

    // ---- MFMA: wave computes 16(dst) x 16(out-col) tile, cols [wave*16, wave*16+16) ----
    int n = lane & 15, quad = lane >> 4;
    const uint16_t* Wb = Wt + (size_t)(wave * 16 + n) * 128;   // B col = out-channel
    f32x4 c = {0.f, 0.f, 0.f, 0.f};
    for (int rel = 0; rel < NREL; ++rel) {
        #pragma unroll
        for (int kb = 0; kb < 4; ++kb) {
            short8 af = *(const short8*)&A[(rel * 16 + n) * AS + kb * 32 + quad * 8];
            short8 bf = *(const short8*)&Wb[rel * 8192 + kb * 32 + quad * 8];
            c = __builtin_amdgcn_mfma_f32_16x16x32_bf16(af, bf, c, 0, 0, 0);
        }
    }
    // root pseudo-relations: A rows = bf16(x[d0+n]) masked by node type (register-built)
    short8 axk[4];
    const float* xr = x + (size_t)(d0 + n) * 128;
    #pragma unroll
    for (int kb = 0; kb < 4; ++kb) {
        float4 u = *(const float4*)(xr + kb * 32 + quad * 8);
        float4 w = *(const float4*)(xr + kb * 32 + quad * 8 + 4);
        uint4 pk;
        pk.x = pack_bf16(u.x, u.y); pk.y = pack_bf16(u.z, u.w);
        pk.z = pack_bf16(w.x, w.y); pk.w = pack_bf16(w.z, w.w);
        axk[kb] = *(short8*)&pk;
    }
    int myNt = nt16[n];
    const short8 z8 = {0, 0, 0, 0, 0, 0, 0, 0};
    #pragma unroll
    for (int tt = 0; tt < NTYP; ++tt) {
        #pragma unroll
        for (int kb = 0; kb < 4; ++kb) {
            short8 am = (myNt == tt) ? axk[kb] : z8;
            short8 bf = *(const short8*)&Wb[(NREL + tt) * 8192 + kb * 32 + quad * 8];
            c = __builtin_amdgcn_mfma_f32_16x16x32_bf16(am, bf, c, 0, 0, 0);
        }
    }

    // epilogue: C col = lane&15 (=n, out-ch), row m = quad*4+rg (dst slot)
    int o = wave * 16 + n;
    #pragma unroll
    for (int rg = 0; rg < 4; ++rg) {
        int m = quad * 4 + rg;
        out[(size_t)(d0 + m) * 64 + o] = c[rg] + b_root[nt16[m] * 64 + o];
    }
}

extern "C" void kernel_launch(void* const* d_in, const int* in_sizes, int n_in,
                              void* d_out, int out_size, void* d_ws, size_t ws_size,
                              hipStream_t stream) {
    const float* x      = (const float*)d_in[0];
    const int*   ei     = (const int*)d_in[1];
    const int*   etype  = (const int*)d_in[2];
    const int*   ntype  = (const int*)d_in[3];
    const float* Wrel   = (const float*)d_in[4];
    const float* Wroot  = (const float*)d_in[5];
    const float* broot  = (const float*)d_in[6];
    float* out = (float*)d_out;

    // workspace layout (~41.4 MB total; well under the 96.6 MB proven-safe mark)
    char* ws = (char*)d_ws;
    size_t p = 0;
    auto take = [&](size_t bytes) { size_t r = p; p += (bytes + 255) & ~(size_t)255; return r; };
    uint16_t* Wt     = (uint16_t*)(ws + take((size_t)NRELT * OC * IC * 2));   // 180 KB
    int*      deg    = (int*)(ws + take((size_t)NSEG * 4));                   // 8.4 MB
    int*      offs   = (int*)(ws + take((size_t)(NSEG + 1) * 4));             // 8.4 MB
    int*      cur    = (int*)(ws + take((size_t)NSEG * 4));                   // 8.4 MB
    int*      bsum   = (int*)(ws + take(16384));
    int*      sorted = (int*)(ws + take((size_t)N_EDGES * 4));                // 16 MB
    (void)ws_size; (void)n_in; (void)in_sizes; (void)out_size;

    const int SCAN_BLKS = (NSEG + 1023) / 1024;   // 2051

    k_cvt_w<<<(NRELT * OC * IC) / 256, 256, 0, stream>>>(Wrel, Wroot, Wt);
    hipMemsetAsync(deg, 0, (size_t)NSEG * 4, stream);
    k_hist<<<(N_EDGES / 4 + 255) / 256, 256, 0, stream>>>(ei, etype, deg);
    k_scan1<<<SCAN_BLKS, 1024, 0, stream>>>(deg, offs, bsum);
    k_scan2<<<1, 1024, 0, stream>>>(bsum, SCAN_BLKS);
    k_scan3<<<(NSEG + 255) / 256, 256, 0, stream>>>(offs, bsum, cur);
    k_scatter<<<(N_EDGES / 4 + 255) / 256, 256, 0, stream>>>(ei, etype, cur, sorted);
    k_main<<<N_NODES / 16, 256, 0, stream>>>(x, Wt, offs, sorted, ntype, broot, out);
}

// Round 5
// 1575.403 us; speedup vs baseline: 2.1275x; 1.0159x over previous
//
#include <hip/hip_runtime.h>
#include <hip/hip_bf16.h>
#include <stdint.h>

#define N_NODES 300000
#define N_EDGES 4000000
#define IC 128
#define OC 64
#define NREL 7
#define NTYP 4
#define NRELT 11                 // 7 relations + 4 root pseudo-relations
#define NSEG (N_NODES * NREL)    // 2,100,000 (dst*7+rel) segments
#define AS 136                   // A-row stride in ushorts (272B, 16B-aligned)
#define SCAN_CHUNK 8192

typedef __attribute__((ext_vector_type(8))) short short8;
typedef __attribute__((ext_vector_type(4))) float f32x4;

__device__ __forceinline__ uint32_t f32_to_bf16_rne(float f) {
    uint32_t b = __float_as_uint(f);
    return (b + 0x7fffu + ((b >> 16) & 1u)) >> 16;
}
__device__ __forceinline__ uint32_t pack_bf16(float lo, float hi) {
    return f32_to_bf16_rne(lo) | (f32_to_bf16_rne(hi) << 16);
}

// ---- K0b: W_rel [7][128][64] ++ W_root [4][128][64] -> Wt bf16 [11][64][128] (o-major, k-contig) ----
__global__ void k_cvt_w(const float* __restrict__ Wrel, const float* __restrict__ Wroot,
                        uint16_t* __restrict__ Wt) {
    int i = blockIdx.x * blockDim.x + threadIdx.x;   // i = rel*8192 + o*128 + k
    int rel = i >> 13, rem = i & 8191, o = rem >> 7, k = rem & 127;
    float v = (rel < NREL) ? Wrel[(rel * IC + k) * OC + o]
                           : Wroot[((rel - NREL) * IC + k) * OC + o];
    Wt[i] = (uint16_t)f32_to_bf16_rne(v);
}

// ---- K1: (dst,rel)-segment histogram, 4 edges/thread ----
__global__ void k_hist(const int* __restrict__ ei, const int* __restrict__ et,
                       int* __restrict__ deg) {
    int i = blockIdx.x * 256 + threadIdx.x;
    if (i >= N_EDGES / 4) return;
    int4 d = ((const int4*)(ei + N_EDGES))[i];
    int4 r = ((const int4*)et)[i];
    atomicAdd(&deg[d.x * 7 + r.x], 1);
    atomicAdd(&deg[d.y * 7 + r.y], 1);
    atomicAdd(&deg[d.z * 7 + r.z], 1);
    atomicAdd(&deg[d.w * 7 + r.w], 1);
}

// ---- K2a: scan, 8 elems/thread (8192/block) ----
__global__ void k_scan1(const int* __restrict__ deg, int* __restrict__ offs,
                        int* __restrict__ bsum) {
    __shared__ int s[1024];
    int t = threadIdx.x;
    size_t base = (size_t)blockIdx.x * SCAN_CHUNK + (size_t)t * 8;
    int v[8];
    if (base + 7 < NSEG) {
        int4 u0 = *(const int4*)(deg + base), u1 = *(const int4*)(deg + base + 4);
        v[0] = u0.x; v[1] = u0.y; v[2] = u0.z; v[3] = u0.w;
        v[4] = u1.x; v[5] = u1.y; v[6] = u1.z; v[7] = u1.w;
    } else {
        #pragma unroll
        for (int j = 0; j < 8; ++j) v[j] = (base + j < NSEG) ? deg[base + j] : 0;
    }
    int run = 0, pre[8];
    #pragma unroll
    for (int j = 0; j < 8; ++j) { pre[j] = run; run += v[j]; }
    s[t] = run; __syncthreads();
    for (int d = 1; d < 1024; d <<= 1) {
        int add = (t >= d) ? s[t - d] : 0;
        __syncthreads();
        s[t] += add;
        __syncthreads();
    }
    int excl = s[t] - run;
    if (base + 7 < NSEG) {
        int4 o0 = {excl + pre[0], excl + pre[1], excl + pre[2], excl + pre[3]};
        int4 o1 = {excl + pre[4], excl + pre[5], excl + pre[6], excl + pre[7]};
        *(int4*)(offs + base) = o0; *(int4*)(offs + base + 4) = o1;
    } else {
        for (int j = 0; j < 8; ++j) if (base + j < NSEG) offs[base + j] = excl + pre[j];
    }
    if (t == 1023) bsum[blockIdx.x] = s[1023];
}

__global__ void k_scan2(int* __restrict__ bsum, int nblk) {
    __shared__ int s[1024];
    int t = threadIdx.x;
    int carry = 0;
    for (int c0 = 0; c0 < nblk; c0 += 1024) {
        int i = c0 + t;
        int v = (i < nblk) ? bsum[i] : 0;
        s[t] = v; __syncthreads();
        for (int d = 1; d < 1024; d <<= 1) {
            int add = (t >= d) ? s[t - d] : 0;
            __syncthreads();
            s[t] += add;
            __syncthreads();
        }
        if (i < nblk) bsum[i] = carry + s[t] - v;
        int tot = s[1023];
        __syncthreads();
        carry += tot;
    }
}

__global__ void k_scan3(int* __restrict__ offs, const int* __restrict__ bsum,
                        int* __restrict__ cur) {
    int i = blockIdx.x * 256 + threadIdx.x;
    if (i < NSEG) {
        int v = offs[i] + bsum[i / SCAN_CHUNK];
        offs[i] = v;
        cur[i] = v;
    }
    if (i == 0) offs[NSEG] = N_EDGES;
}

// ---- K3: scatter src into (dst,rel)-sorted order ----
__global__ void k_scatter(const int* __restrict__ ei, const int* __restrict__ et,
                          int* __restrict__ cur, int* __restrict__ sorted) {
    int i = blockIdx.x * 256 + threadIdx.x;
    if (i >= N_EDGES / 4) return;
    int4 sv = ((const int4*)ei)[i];
    int4 dv = ((const int4*)(ei + N_EDGES))[i];
    int4 rv = ((const int4*)et)[i];
    { int pos = atomicAdd(&cur[dv.x * 7 + rv.x], 1); sorted[pos] = sv.x; }
    { int pos = atomicAdd(&cur[dv.y * 7 + rv.y], 1); sorted[pos] = sv.y; }
    { int pos = atomicAdd(&cur[dv.z * 7 + rv.z], 1); sorted[pos] = sv.z; }
    { int pos = atomicAdd(&cur[dv.w * 7 + rv.w], 1); sorted[pos] = sv.w; }
}

// ---- K4: software-pipelined atomic-free aggregate + MFMA. 1 block = 16 dst, wave owns 4. ----
__global__ __launch_bounds__(256, 4)
void k_main(const float* __restrict__ x, const uint16_t* __restrict__ Wt,
            const int* __restrict__ offs, const int* __restrict__ sorted,
            const int* __restrict__ node_type, const float* __restrict__ b_root,
            float* __restrict__ out) {
    __shared__ uint16_t A[NREL * 16 * AS];   // 30,464 B; row = rel*16 + slot, k-contig
    __shared__ int nt16[16];
    int t = threadIdx.x, lane = t & 63, wave = t >> 6;
    int d0 = blockIdx.x * 16;
    if (t < 16) nt16[t] = node_type[d0 + t];
    uint32_t* Pk = (uint32_t*)A;             // row stride 68 uints

    // wave's 28 segment boundaries
    int segbase = (d0 + wave * 4) * 7;
    int off_l = (lane < 29) ? offs[segbase + lane] : 0;
    // per-lane (lane<28): segment inv count and target A row
    int end_l = __shfl(off_l, lane + 1);
    float inv_l = 1.0f / (float)max(end_l - off_l, 1);
    int row_l = ((lane % 7) * 16 + wave * 4 + lane / 7) * 68;
    int mybase = __builtin_amdgcn_readfirstlane(__shfl(off_l, 0));
    int myend  = __builtin_amdgcn_readfirstlane(__shfl(off_l, 28));
    int L = myend - mybase;                  // scalar

    // edge src ids, lane-strided (covers first 128 edges; >128 is ~never)
    int rec0 = (mybase + lane < myend) ? sorted[mybase + lane] : 0;
    int rec1 = (mybase + 64 + lane < myend) ? sorted[mybase + 64 + lane] : 0;

    const float* xl = x + lane * 2;
    float a0 = 0.f, a1 = 0.f;
    int sp = 0;
    int e_end = __shfl(off_l, 1);

    // ---- prime 8-deep ring ----
    float2 ring[8];
    #pragma unroll
    for (int j = 0; j < 8; ++j) {
        if (j < L) {
            int src = __builtin_amdgcn_readlane(rec0, j);
            ring[j] = *(const float2*)(xl + (size_t)src * 128);
        }
    }

    int Lf = (L < 128) ? L : 128;
    for (int k0 = 0; k0 < Lf; k0 += 8) {
        #pragma unroll
        for (int j = 0; j < 8; ++j) {
            int k = k0 + j;
            if (k < Lf) {
                // flush segments ending here (uniform, usually 0-1 iterations)
                while (mybase + k == e_end && sp < 27) {
                    float inv = __shfl(inv_l, sp);
                    int row = __shfl(row_l, sp);
                    Pk[row + lane] = pack_bf16(a0 * inv, a1 * inv);
                    a0 = 0.f; a1 = 0.f;
                    ++sp;
                    e_end = __shfl(off_l, sp + 1);
                }
                a0 += ring[j].x; a1 += ring[j].y;
                int kn = k + 8;
                if (kn < Lf) {               // issue edge k+8 into this slot
                    int rsel = (kn < 64) ? rec0 : rec1;
                    int src = __builtin_amdgcn_readlane(rsel, kn & 63);
                    ring[j] = *(const float2*)(xl + (size_t)src * 128);
                }
            }
        }
    }
    // rare slow tail: edges [128, L)
    for (int k = 128; k < L; ++k) {
        int src = sorted[mybase + k];        // uniform broadcast load
        float2 v = *(const float2*)(xl + (size_t)src * 128);
        while (mybase + k == e_end && sp < 27) {
            float inv = __shfl(inv_l, sp);
            int row = __shfl(row_l, sp);
            Pk[row + lane] = pack_bf16(a0 * inv, a1 * inv);
            a0 = 0.f; a1 = 0.f;
            ++sp;
            e_end = __shfl(off_l, sp + 1);
        }
        a0 += v.x; a1 += v.y;
    }
    // final flush: open segment + remaining (possibly empty) segments
    for (; sp < 28; ++sp) {
        float inv = __shfl(inv_l, sp);
        int row = __shfl(row_l, sp);
        Pk[row + lane] = pack_bf16(a0 * inv, a1 * inv);
        a0 = 0.f; a1 = 0.f;
    }
    __syncthreads();

    // ---- MFMA: wave computes 16(dst) x 16(out-col) tile, cols [wave*16, wave*16+16) ----
    int n = lane & 15, quad = lane >> 4;
    const uint16_t* Wb = Wt + (size_t)(wave * 16 + n) * 128;   // B col = out-channel
    f32x4 c = {0.f, 0.f, 0.f, 0.f};
    for (int rel = 0; rel < NREL; ++rel) {
        #pragma unroll
        for (int kb = 0; kb < 4; ++kb) {
            short8 af = *(const short8*)&A[(rel * 16 + n) * AS + kb * 32 + quad * 8];
            short8 bf = *(const short8*)&Wb[rel * 8192 + kb * 32 + quad * 8];
            c = __builtin_amdgcn_mfma_f32_16x16x32_bf16(af, bf, c, 0, 0, 0);
        }
    }
    // root pseudo-relations: A rows = bf16(x[d0+n]) masked by node type (register-built)
    short8 axk[4];
    const float* xr = x + (size_t)(d0 + n) * 128;
    #pragma unroll
    for (int kb = 0; kb < 4; ++kb) {
        float4 u = *(const float4*)(xr + kb * 32 + quad * 8);
        float4 w = *(const float4*)(xr + kb * 32 + quad * 8 + 4);
        uint4 pk;
        pk.x = pack_bf16(u.x, u.y); pk.y = pack_bf16(u.z, u.w);
        pk.z = pack_bf16(w.x, w.y); pk.w = pack_bf16(w.z, w.w);
        axk[kb] = *(short8*)&pk;
    }
    int myNt = nt16[n];
    const short8 z8 = {0, 0, 0, 0, 0, 0, 0, 0};
    #pragma unroll
    for (int tt = 0; tt < NTYP; ++tt) {
        #pragma unroll
        for (int kb = 0; kb < 4; ++kb) {
            short8 am = (myNt == tt) ? axk[kb] : z8;
            short8 bf = *(const short8*)&Wb[(NREL + tt) * 8192 + kb * 32 + quad * 8];
            c = __builtin_amdgcn_mfma_f32_16x16x32_bf16(am, bf, c, 0, 0, 0);
        }
    }

    // epilogue: C col = lane&15 (=n, out-ch), row m = quad*4+rg (dst slot)
    int o = wave * 16 + n;
    #pragma unroll
    for (int rg = 0; rg < 4; ++rg) {
        int m = quad * 4 + rg;
        out[(size_t)(d0 + m) * 64 + o] = c[rg] + b_root[nt16[m] * 64 + o];
    }
}

extern "C" void kernel_launch(void* const* d_in, const int* in_sizes, int n_in,
                              void* d_out, int out_size, void* d_ws, size_t ws_size,
                              hipStream_t stream) {
    const float* x      = (const float*)d_in[0];
    const int*   ei     = (const int*)d_in[1];
    const int*   etype  = (const int*)d_in[2];
    const int*   ntype  = (const int*)d_in[3];
    const float* Wrel   = (const float*)d_in[4];
    const float* Wroot  = (const float*)d_in[5];
    const float* broot  = (const float*)d_in[6];
    float* out = (float*)d_out;

    // workspace layout (~41.4 MB total; well under the 96.6 MB proven-safe mark)
    char* ws = (char*)d_ws;
    size_t p = 0;
    auto take = [&](size_t bytes) { size_t r = p; p += (bytes + 255) & ~(size_t)255; return r; };
    uint16_t* Wt     = (uint16_t*)(ws + take((size_t)NRELT * OC * IC * 2));   // 180 KB
    int*      deg    = (int*)(ws + take((size_t)NSEG * 4));                   // 8.4 MB
    int*      offs   = (int*)(ws + take((size_t)(NSEG + 1) * 4));             // 8.4 MB
    int*      cur    = (int*)(ws + take((size_t)NSEG * 4));                   // 8.4 MB
    int*      bsum   = (int*)(ws + take(16384));
    int*      sorted = (int*)(ws + take((size_t)N_EDGES * 4));                // 16 MB
    (void)ws_size; (void)n_in; (void)in_sizes; (void)out_size;

    const int SCAN_BLKS = (NSEG + SCAN_CHUNK - 1) / SCAN_CHUNK;   // 257

    k_cvt_w<<<(NRELT * OC * IC) / 256, 256, 0, stream>>>(Wrel, Wroot, Wt);
    hipMemsetAsync(deg, 0, (size_t)NSEG * 4, stream);
    k_hist<<<(N_EDGES / 4 + 255) / 256, 256, 0, stream>>>(ei, etype, deg);
    k_scan1<<<SCAN_BLKS, 1024, 0, stream>>>(deg, offs, bsum);
    k_scan2<<<1, 1024, 0, stream>>>(bsum, SCAN_BLKS);
    k_scan3<<<(NSEG + 255) / 256, 256, 0, stream>>>(offs, bsum, cur);
    k_scatter<<<(N_EDGES / 4 + 255) / 256, 256, 0, stream>>>(ei, etype, cur, sorted);
    k_main<<<N_NODES / 16, 256, 0, stream>>>(x, Wt, offs, sorted, ntype, broot, out);
}